// Round 14
// baseline (193.379 us; speedup 1.0000x reference)
//
#include <hip/hip_runtime.h>

#define NN   10000
#define EE   160000
#define CINC 32
#define COUTC 32
#define RRR  6
#define MMM  3
#define RM   (RRR*MMM)      // 18
#define KK   (RM*CINC)      // 576
#define NPB  4              // nodes per block (one wave each), 256 threads
#define CE   8              // edges staged per node per chunk
#define CAP  64             // fixed bucket capacity per node (mean degree 16)
#define AROW 592            // agg row stride in bf16 elems (576 + 16 pad)
#define EPSV 1e-8f

typedef __attribute__((ext_vector_type(8))) short bf16x8;
typedef __attribute__((ext_vector_type(4))) float f32x4;

__device__ inline short f2bf(float f) {            // round-to-nearest-even
    unsigned u = __float_as_uint(f);
    u = (u + 0x7FFF + ((u >> 16) & 1)) >> 16;
    return (short)u;
}

// ---------------- build: bf16 weight planes + direct bucket scatter ----------------
// cursor[] pre-zeroed by hipMemsetAsync. Buckets hold (src,eid) as int2.

__global__ void __launch_bounds__(256)
k_build(const int* __restrict__ edges, int* __restrict__ cursor,
        const float* __restrict__ w1, const float* __restrict__ off1,
        const float* __restrict__ w2, const float* __restrict__ off2,
        short* __restrict__ Wcb1, short* __restrict__ Wcb2,
        int2* __restrict__ sei)
{
    int i = blockIdx.x*blockDim.x + threadIdx.x;
    if (i < KK*COUTC) {
        int d = i & 31;
        int k = i >> 5;                 // rm*32 + c
        int c = k & 31;
        float o1 = off1[c*COUTC + d];
        float o2 = off2[c*COUTC + d];
        float s1 = sinf(o1), c1 = cosf(o1);
        float s2 = sinf(o2), c2 = cosf(o2);
        Wcb1[d*KK + k]          = f2bf(w1[i]*c1);
        Wcb1[KK*COUTC + d*KK+k] = f2bf(w1[i]*s1);
        Wcb2[d*KK + k]          = f2bf(w2[i]*c2);
        Wcb2[KK*COUTC + d*KK+k] = f2bf(w2[i]*s2);
    }
    if (i < EE) {
        int src = edges[2*i];
        int tgt = edges[2*i+1];
        int pos = atomicAdd(&cursor[tgt], 1);
        if (pos < CAP) sei[tgt*CAP + pos] = make_int2(src, i);
    }
}

// ---------------- fused conv: pipelined fp32 edge phase + bf16 MFMA einsum ----------------
// 4 nodes/block, 256 threads = 4 waves, 1 node/wave (small blocks: 8 blocks/CU
// by LDS, fine drain granularity, barriers couple only 4 waves). Per-node
// (src,eid) in registers (lane l = slot l). Chunk loop software-pipelined:
// issue chunk k+1's global loads -> compute chunk k from LDS (double-buffered)
// -> ds_write chunk k+1. ALL __shfl broadcasts unconditional (ds_bpermute
// reads garbage from EXEC-inactive source lanes); only dependent global loads
// predicated. Einsum via mfma_f32_16x16x32_bf16, rm-split {5,5,4,4} over the
// 4 waves; cross-wave reduce via LDS dump.

template<bool FINAL>
__global__ void __launch_bounds__(256)
k_conv(const float2* __restrict__ xin,      // (NN,32) complex input
       const int*  __restrict__ cnts,       // (NN) per-node edge count
       const int2* __restrict__ sei,        // (NN*CAP) (src,eid) buckets
       const float4* __restrict__ stenc4,   // (EE,9) float4 = (EE,18) complex
       const short* __restrict__ Wcb,       // [re|im][32][576] bf16
       const float* __restrict__ bias,      // (32)
       const float2* __restrict__ xres,     // (NN,32) original xc (FINAL)
       const float2* __restrict__ resw,     // (32,32) complex (FINAL)
       float2* __restrict__ out)            // (NN,32) complex
{
    __shared__ __align__(16) short aggS[2*NPB*AROW];     // 9472 B; later dump
    __shared__ __align__(16) float4 sten[NPB*2*CE*9];    // 9216 B dbuf stage
    int t = threadIdx.x;
    int g = t >> 6;                     // wave = node slot 0..3
    int l = t & 63;
    int n0 = blockIdx.x*NPB;

    // ---- edge aggregation (fp32, pipelined) ----
    {
        int n = n0 + g;
        int c = l & 31;
        int h = l >> 5;                 // half: alternate edges
        int cnt = cnts[n]; if (cnt > CAP) cnt = CAP;
        int beg = n*CAP;
        int srcAll = 0, eidAll = 0;
        if (l < cnt) { int2 v = sei[beg + l]; srcAll = v.x; eidAll = v.y; }

        // staging slot assignment (loop-invariant): lane covers idx l and l+64
        int e0 = l/9,      cp0 = l - 9*e0;
        int e1 = (l+64)/9, cp1 = (l+64) - 9*e1;

        float4* bufA = sten + g*(2*CE*9);
        float4* bufB = bufA + CE*9;

        float2 acc[RM];
        #pragma unroll
        for (int k = 0; k < RM; ++k) acc[k] = make_float2(0.f, 0.f);

        int nchunks = (cnt + CE - 1) / CE;
        float4 r0 = make_float4(0,0,0,0), r1 = r0;
        float2 xq[CE/2], xn[CE/2];

        auto stage_load = [&](int ck) {
            int ne = cnt - ck*CE; if (ne > CE) ne = CE;
            int nf4 = ne*9;
            int s0i = ck*CE + e0; if (s0i > 63) s0i = 63;
            int s1i = ck*CE + e1; if (s1i > 63) s1i = 63;
            int eidA = __shfl(eidAll, s0i, 64);      // unconditional
            int eidB = __shfl(eidAll, s1i, 64);
            r0 = make_float4(0,0,0,0); r1 = r0;
            if (l < nf4)      r0 = stenc4[(size_t)eidA*9 + cp0];
            if (l + 64 < nf4) r1 = stenc4[(size_t)eidB*9 + cp1];
        };
        auto load_x = [&](int ck, float2* xr) {
            int ne = cnt - ck*CE; if (ne > CE) ne = CE;
            #pragma unroll
            for (int i = 0; i < CE/2; ++i) {
                int le = h + 2*i;
                int sl = ck*CE + le; if (sl > 63) sl = 63;
                int s = __shfl(srcAll, sl, 64);      // unconditional
                float2 v = make_float2(0.f, 0.f);
                if (le < ne) v = xin[(size_t)s*CINC + c];
                xr[i] = v;
            }
        };
        auto stage_write = [&](float4* dst, int ck) {
            int ne = cnt - ck*CE; if (ne > CE) ne = CE;
            int nf4 = ne*9;
            if (l < nf4)      dst[l] = r0;
            if (l + 64 < nf4) dst[l+64] = r1;
        };

        if (nchunks > 0) {
            stage_load(0); load_x(0, xq); stage_write(bufA, 0);
            for (int ck = 0; ck < nchunks; ++ck) {
                float4* cur = (ck & 1) ? bufB : bufA;
                float4* nxt = (ck & 1) ? bufA : bufB;
                bool more = (ck + 1 < nchunks);
                if (more) { stage_load(ck+1); load_x(ck+1, xn); }
                int ne = cnt - ck*CE; if (ne > CE) ne = CE;
                #pragma unroll
                for (int i = 0; i < CE/2; ++i) {
                    int le = h + 2*i;
                    if (le < ne) {
                        const float4* sp = cur + le*9;
                        float2 xv = xq[i];
                        #pragma unroll
                        for (int j = 0; j < 9; ++j) {
                            float4 s = sp[j];
                            acc[2*j].x   = fmaf(s.x, xv.x, fmaf(-s.y, xv.y, acc[2*j].x));
                            acc[2*j].y   = fmaf(s.x, xv.y, fmaf( s.y, xv.x, acc[2*j].y));
                            acc[2*j+1].x = fmaf(s.z, xv.x, fmaf(-s.w, xv.y, acc[2*j+1].x));
                            acc[2*j+1].y = fmaf(s.z, xv.y, fmaf( s.w, xv.x, acc[2*j+1].y));
                        }
                    }
                }
                if (more) {
                    stage_write(nxt, ck+1);
                    #pragma unroll
                    for (int i = 0; i < CE/2; ++i) xq[i] = xn[i];
                }
            }
        }

        #pragma unroll
        for (int k = 0; k < RM; ++k) {
            acc[k].x += __shfl_down(acc[k].x, 32, 64);
            acc[k].y += __shfl_down(acc[k].y, 32, 64);
        }
        if (h == 0) {                   // bf16 agg rows (deg==0 -> zeros)
            #pragma unroll
            for (int k = 0; k < RM; ++k) {
                aggS[g*AROW + k*32 + c]            = f2bf(acc[k].x);
                aggS[NPB*AROW + g*AROW + k*32 + c] = f2bf(acc[k].y);
            }
        }
    }
    __syncthreads();

    // ---- einsum via MFMA: D[m][d] = sum_k agg[m][k] * Wc[k][d] ----
    int quad = l >> 4;
    int nn16 = l & 15;
    int mrow = (nn16 < NPB) ? nn16 : NPB-1;       // A rows >=4 dup of 3 (ignored)
    int rm0 = (g < 2) ? 5*g : 4*g + 2;            // {0,5,10,14}
    int nrm = (g < 2) ? 5 : 4;
    const short* aggR = aggS;
    const short* aggI = aggS + NPB*AROW;
    const short* Wr = Wcb;
    const short* Wi = Wcb + KK*COUTC;

    f32x4 Prr[2], Pii[2], Pri[2], Pir[2];
    #pragma unroll
    for (int nt = 0; nt < 2; ++nt) {
        Prr[nt] = (f32x4)(0.f); Pii[nt] = (f32x4)(0.f);
        Pri[nt] = (f32x4)(0.f); Pir[nt] = (f32x4)(0.f);
    }
    for (int r = rm0; r < rm0 + nrm; ++r) {
        int koff = r*32 + quad*8;
        bf16x8 ar = *(const bf16x8*)(aggR + mrow*AROW + koff);
        bf16x8 ai = *(const bf16x8*)(aggI + mrow*AROW + koff);
        #pragma unroll
        for (int nt = 0; nt < 2; ++nt) {
            int d = nt*16 + nn16;
            bf16x8 br = *(const bf16x8*)(Wr + d*KK + koff);
            bf16x8 bi = *(const bf16x8*)(Wi + d*KK + koff);
            Prr[nt] = __builtin_amdgcn_mfma_f32_16x16x32_bf16(ar, br, Prr[nt], 0, 0, 0);
            Pii[nt] = __builtin_amdgcn_mfma_f32_16x16x32_bf16(ai, bi, Pii[nt], 0, 0, 0);
            Pri[nt] = __builtin_amdgcn_mfma_f32_16x16x32_bf16(ar, bi, Pri[nt], 0, 0, 0);
            Pir[nt] = __builtin_amdgcn_mfma_f32_16x16x32_bf16(ai, br, Pir[nt], 0, 0, 0);
        }
    }
    __syncthreads();                    // all agg reads done; reuse as dump

    // ---- dump partials: [wave][m][d] float2; D rows m = quad*4+reg, only
    // quad==0 holds valid node rows 0..3 ----
    float2* dump = (float2*)aggS;       // 4*4*32*8 = 4096 B
    if (quad == 0) {
        #pragma unroll
        for (int reg = 0; reg < 4; ++reg) {
            #pragma unroll
            for (int nt = 0; nt < 2; ++nt) {
                int d = nt*16 + nn16;
                dump[((size_t)g*NPB + reg)*COUTC + d] =
                    make_float2(Prr[nt][reg] - Pii[nt][reg],
                                Pri[nt][reg] + Pir[nt][reg]);
            }
        }
    }
    __syncthreads();

    // ---- reduce 4 waves, residual, nonlinearity ----
    if (t < NPB*COUTC) {
        int m = t >> 5, d = t & 31;
        int n = n0 + m;
        float2 hv = make_float2(0.f, 0.f);
        #pragma unroll
        for (int w = 0; w < NPB; ++w) {
            float2 v = dump[((size_t)w*NPB + m)*COUTC + d];
            hv.x += v.x; hv.y += v.y;
        }
        if (FINAL) {
            const float2* xr = xres + (size_t)n * CINC;
            #pragma unroll
            for (int c = 0; c < CINC; ++c) {
                float2 xv = xr[c];
                float2 w = resw[c*COUTC + d];
                hv.x += xv.x*w.x - xv.y*w.y;
                hv.y += xv.x*w.y + xv.y*w.x;
            }
        }
        float mag = sqrtf(hv.x*hv.x + hv.y*hv.y);
        float num = mag + bias[d]; if (num < 0.f) num = 0.f;
        float den = (mag > EPSV) ? mag : EPSV;
        float f = num / den;
        out[(size_t)n*COUTC + d] = make_float2(f*hv.x, f*hv.y);
    }
}

// ---------------- launch ----------------

extern "C" void kernel_launch(void* const* d_in, const int* in_sizes, int n_in,
                              void* d_out, int out_size, void* d_ws, size_t ws_size,
                              hipStream_t stream) {
    const float2* xc   = (const float2*)d_in[0];   // (N,32,2) -> complex
    const int*   edges = (const int*)  d_in[1];    // (E,2)
    const float4* stenc4 = (const float4*)d_in[2]; // (E,6,3,2) -> (E,9) float4
    const float* w1    = (const float*)d_in[3];
    const float* off1  = (const float*)d_in[4];
    const float* b1    = (const float*)d_in[5];
    const float* w2    = (const float*)d_in[6];
    const float* off2  = (const float*)d_in[7];
    const float* b2    = (const float*)d_in[8];
    const float2* resw = (const float2*)d_in[9];   // (32,32) complex
    float2* out = (float2*)d_out;

    char* ws = (char*)d_ws;
    size_t o = 0;
    auto alloc = [&](size_t bytes) {
        o = (o + 255) & ~(size_t)255;
        size_t r = o; o += bytes; return r;
    };
    int*    cursor = (int*)  (ws + alloc(NN*sizeof(int)));
    int2*   sei    = (int2*) (ws + alloc((size_t)NN*CAP*sizeof(int2)));
    short*  Wcb1   = (short*)(ws + alloc((size_t)2*KK*COUTC*sizeof(short)));
    short*  Wcb2   = (short*)(ws + alloc((size_t)2*KK*COUTC*sizeof(short)));
    float2* h      = (float2*)(ws + alloc((size_t)NN*COUTC*sizeof(float2)));
    (void)ws_size; (void)in_sizes; (void)n_in; (void)out_size;

    hipMemsetAsync(cursor, 0, NN*sizeof(int), stream);
    k_build<<<(EE+255)/256, 256, 0, stream>>>(edges, cursor, w1, off1, w2, off2,
                                              Wcb1, Wcb2, sei);

    k_conv<false><<<NN/NPB, 256, 0, stream>>>(xc, cursor, sei, stenc4,
                                              Wcb1, b1, nullptr, nullptr, h);
    k_conv<true> <<<NN/NPB, 256, 0, stream>>>(h, cursor, sei, stenc4,
                                              Wcb2, b2, xc, resw, out);
}

// Round 15
// 180.530 us; speedup vs baseline: 1.0712x; 1.0712x over previous
//
#include <hip/hip_runtime.h>

#define NN   10000
#define EE   160000
#define CINC 32
#define COUTC 32
#define RRR  6
#define MMM  3
#define RM   (RRR*MMM)      // 18
#define KK   (RM*CINC)      // 576
#define NPB  8              // nodes per block (one wave each)
#define CE   8              // edges staged per node per chunk
#define CAP  64             // fixed bucket capacity per node (mean degree 16)
#define AROW 592            // agg row stride in bf16 elems (576 + 16 pad)
#define SBS  40             // bf16 stencil row stride in shorts (36 valid + 4 pad = 80B)
#define EPSV 1e-8f

typedef __attribute__((ext_vector_type(8))) short bf16x8;
typedef __attribute__((ext_vector_type(4))) float f32x4;

__device__ inline short f2bf(float f) {            // round-to-nearest-even
    unsigned u = __float_as_uint(f);
    u = (u + 0x7FFF + ((u >> 16) & 1)) >> 16;
    return (short)u;
}

// ---------------- build: bf16 weight planes + bf16 stencil + bucket scatter ----------------
// cursor[] pre-zeroed by hipMemsetAsync. Grid covers EE*9 (stencil cvt lanes).
// stenB: per-edge 36 bf16 (18 complex, interleaved re,im) in 80B padded rows —
// halves the per-conv stencil fetch (the conv is outstanding-request bound).

__global__ void __launch_bounds__(256)
k_build(const int* __restrict__ edges, int* __restrict__ cursor,
        const float* __restrict__ w1, const float* __restrict__ off1,
        const float* __restrict__ w2, const float* __restrict__ off2,
        short* __restrict__ Wcb1, short* __restrict__ Wcb2,
        int2* __restrict__ sei,
        const float4* __restrict__ stenc4, short* __restrict__ stenB)
{
    int i = blockIdx.x*blockDim.x + threadIdx.x;
    if (i < KK*COUTC) {
        int d = i & 31;
        int k = i >> 5;                 // rm*32 + c
        int c = k & 31;
        float o1 = off1[c*COUTC + d];
        float o2 = off2[c*COUTC + d];
        float s1 = sinf(o1), c1 = cosf(o1);
        float s2 = sinf(o2), c2 = cosf(o2);
        Wcb1[d*KK + k]          = f2bf(w1[i]*c1);
        Wcb1[KK*COUTC + d*KK+k] = f2bf(w1[i]*s1);
        Wcb2[d*KK + k]          = f2bf(w2[i]*c2);
        Wcb2[KK*COUTC + d*KK+k] = f2bf(w2[i]*s2);
    }
    if (i < EE) {
        int src = edges[2*i];
        int tgt = edges[2*i+1];
        int pos = atomicAdd(&cursor[tgt], 1);
        if (pos < CAP) sei[tgt*CAP + pos] = make_int2(src, i);
    }
    if (i < EE*9) {                     // stencil fp32 -> bf16 (4 vals / thread)
        float4 v = stenc4[i];
        int e = i / 9, p = i - 9*e;
        unsigned a = ((unsigned)(unsigned short)f2bf(v.y) << 16) |
                      (unsigned)(unsigned short)f2bf(v.x);
        unsigned b = ((unsigned)(unsigned short)f2bf(v.w) << 16) |
                      (unsigned)(unsigned short)f2bf(v.z);
        *(uint2*)(stenB + (size_t)e*SBS + p*4) = make_uint2(a, b);
    }
}

// ---------------- degree counting-sort, DESCENDING (single block) ----------------

__global__ void __launch_bounds__(1024)
k_order(const int* __restrict__ cnts, int* __restrict__ order) {
    __shared__ int bins[CAP+1];
    __shared__ int base[CAP+1];
    int t = threadIdx.x;
    if (t <= CAP) bins[t] = 0;
    __syncthreads();
    for (int n = t; n < NN; n += 1024) {
        int d = cnts[n]; if (d > CAP) d = CAP;
        atomicAdd(&bins[d], 1);
    }
    __syncthreads();
    if (t == 0) {
        int run = 0;
        for (int b = CAP; b >= 0; --b) { base[b] = run; run += bins[b]; }
    }
    __syncthreads();
    for (int n = t; n < NN; n += 1024) {
        int d = cnts[n]; if (d > CAP) d = CAP;
        int r = atomicAdd(&base[d], 1);
        order[r] = n;
    }
}

// ---------------- fused conv: pipelined edge phase (bf16-staged stencil) + MFMA einsum ----------------
// 8 nodes/block, 512 threads = 8 waves, 1 node/wave. Chunk staging loads the
// bf16 stencil (40 x 16B slots per chunk, ONE load instr per wave) and expands
// to fp32 during the LDS write, so the FMA loop is identical to the fp32
// version. All __shfl broadcasts unconditional (EXEC-inactive source lanes
// return garbage); only dependent global loads predicated. Einsum via
// mfma_f32_16x16x32_bf16, rm-split {3,3,2,2,2,2,2,2} over 8 waves.

template<bool FINAL>
__global__ void __launch_bounds__(512)
k_conv(const float2* __restrict__ xin,      // (NN,32) complex input
       const int*  __restrict__ cnts,       // (NN) per-node edge count
       const int*  __restrict__ order,      // (NN) degree-sorted node ids (desc)
       const int2* __restrict__ sei,        // (NN*CAP) (src,eid) buckets
       const uint4* __restrict__ stenB4,    // (EE,5) uint4 = 80B bf16 rows
       const short* __restrict__ Wcb,       // [re|im][32][576] bf16
       const float* __restrict__ bias,      // (32)
       const float2* __restrict__ xres,     // (NN,32) original xc (FINAL)
       const float2* __restrict__ resw,     // (32,32) complex (FINAL)
       float2* __restrict__ out)            // (NN,32) complex
{
    __shared__ __align__(16) short aggS[2*NPB*AROW];     // 18944 B; later dump
    __shared__ __align__(16) float4 sten[NPB*2*CE*10];   // 20480 B dbuf (fp32 rows, 160B/edge)
    __shared__ int nid[NPB];
    int t = threadIdx.x;
    int g = t >> 6;                     // wave = node slot 0..7
    int l = t & 63;

    if (t < NPB) nid[t] = order[blockIdx.x*NPB + t];
    __syncthreads();

    // ---- edge aggregation (fp32 accumulate, pipelined) ----
    {
        int n = nid[g];
        int c = l & 31;
        int h = l >> 5;                 // half: alternate edges
        int cnt = cnts[n]; if (cnt > CAP) cnt = CAP;
        int beg = n*CAP;
        int srcAll = 0, eidAll = 0;
        if (l < cnt) { int2 v = sei[beg + l]; srcAll = v.x; eidAll = v.y; }

        // staging: slot s covers edge e0 = s/5, 16B part cp0 = s%5 (lanes 0..39)
        int e0 = l/5, cp0 = l - 5*e0;

        float4* bufA = sten + g*(2*CE*10);
        float4* bufB = bufA + CE*10;

        float2 acc[RM];
        #pragma unroll
        for (int k = 0; k < RM; ++k) acc[k] = make_float2(0.f, 0.f);

        int nchunks = (cnt + CE - 1) / CE;
        uint4 r0 = make_uint4(0,0,0,0);
        float2 xq[CE/2], xn[CE/2];

        auto stage_load = [&](int ck) {
            int ne = cnt - ck*CE; if (ne > CE) ne = CE;
            int nsl = ne*5;
            int s0i = ck*CE + e0; if (s0i > 63) s0i = 63;
            int eidA = __shfl(eidAll, s0i, 64);      // unconditional
            r0 = make_uint4(0,0,0,0);
            if (l < nsl) r0 = stenB4[(size_t)eidA*5 + cp0];
        };
        auto load_x = [&](int ck, float2* xr) {
            int ne = cnt - ck*CE; if (ne > CE) ne = CE;
            #pragma unroll
            for (int i = 0; i < CE/2; ++i) {
                int le = h + 2*i;
                int sl = ck*CE + le; if (sl > 63) sl = 63;
                int s = __shfl(srcAll, sl, 64);      // unconditional
                float2 v = make_float2(0.f, 0.f);
                if (le < ne) v = xin[(size_t)s*CINC + c];
                xr[i] = v;
            }
        };
        auto stage_write = [&](float4* dst, int ck) {
            int ne = cnt - ck*CE; if (ne > CE) ne = CE;
            int nsl = ne*5;
            if (l < nsl) {
                // expand 8 bf16 -> 8 fp32 (memory order re,im interleaved)
                float4 fa = make_float4(__uint_as_float(r0.x << 16),
                                        __uint_as_float(r0.x & 0xFFFF0000u),
                                        __uint_as_float(r0.y << 16),
                                        __uint_as_float(r0.y & 0xFFFF0000u));
                float4 fb = make_float4(__uint_as_float(r0.z << 16),
                                        __uint_as_float(r0.z & 0xFFFF0000u),
                                        __uint_as_float(r0.w << 16),
                                        __uint_as_float(r0.w & 0xFFFF0000u));
                float4* p = dst + e0*10 + cp0*2;
                p[0] = fa;
                p[1] = fb;
            }
        };

        if (nchunks > 0) {
            stage_load(0); load_x(0, xq); stage_write(bufA, 0);
            for (int ck = 0; ck < nchunks; ++ck) {
                float4* cur = (ck & 1) ? bufB : bufA;
                float4* nxt = (ck & 1) ? bufA : bufB;
                bool more = (ck + 1 < nchunks);
                if (more) { stage_load(ck+1); load_x(ck+1, xn); }
                int ne = cnt - ck*CE; if (ne > CE) ne = CE;
                #pragma unroll
                for (int i = 0; i < CE/2; ++i) {
                    int le = h + 2*i;
                    if (le < ne) {
                        const float4* sp = cur + le*10;
                        float2 xv = xq[i];
                        #pragma unroll
                        for (int j = 0; j < 9; ++j) {
                            float4 s = sp[j];
                            acc[2*j].x   = fmaf(s.x, xv.x, fmaf(-s.y, xv.y, acc[2*j].x));
                            acc[2*j].y   = fmaf(s.x, xv.y, fmaf( s.y, xv.x, acc[2*j].y));
                            acc[2*j+1].x = fmaf(s.z, xv.x, fmaf(-s.w, xv.y, acc[2*j+1].x));
                            acc[2*j+1].y = fmaf(s.z, xv.y, fmaf( s.w, xv.x, acc[2*j+1].y));
                        }
                    }
                }
                if (more) {
                    stage_write(nxt, ck+1);
                    #pragma unroll
                    for (int i = 0; i < CE/2; ++i) xq[i] = xn[i];
                }
            }
        }

        #pragma unroll
        for (int k = 0; k < RM; ++k) {
            acc[k].x += __shfl_down(acc[k].x, 32, 64);
            acc[k].y += __shfl_down(acc[k].y, 32, 64);
        }
        if (h == 0) {                   // bf16 agg rows (deg==0 -> zeros)
            #pragma unroll
            for (int k = 0; k < RM; ++k) {
                aggS[g*AROW + k*32 + c]            = f2bf(acc[k].x);
                aggS[NPB*AROW + g*AROW + k*32 + c] = f2bf(acc[k].y);
            }
        }
    }
    __syncthreads();

    // ---- einsum via MFMA: D[m][d] = sum_k agg[m][k] * Wc[k][d] ----
    int quad = l >> 4;
    int nn16 = l & 15;
    int mrow = (nn16 < NPB) ? nn16 : NPB-1;       // rows >=8 ignored (dup of 7)
    int rm0 = (g < 2) ? 3*g : 2*g + 2;            // waves 0-1: 3 rm, else 2 rm
    int nrm = (g < 2) ? 3 : 2;
    const short* aggR = aggS;
    const short* aggI = aggS + NPB*AROW;
    const short* Wr = Wcb;
    const short* Wi = Wcb + KK*COUTC;

    f32x4 Prr[2], Pii[2], Pri[2], Pir[2];
    #pragma unroll
    for (int nt = 0; nt < 2; ++nt) {
        Prr[nt] = (f32x4)(0.f); Pii[nt] = (f32x4)(0.f);
        Pri[nt] = (f32x4)(0.f); Pir[nt] = (f32x4)(0.f);
    }
    for (int r = rm0; r < rm0 + nrm; ++r) {
        int koff = r*32 + quad*8;
        bf16x8 ar = *(const bf16x8*)(aggR + mrow*AROW + koff);
        bf16x8 ai = *(const bf16x8*)(aggI + mrow*AROW + koff);
        #pragma unroll
        for (int nt = 0; nt < 2; ++nt) {
            int d = nt*16 + nn16;
            bf16x8 br = *(const bf16x8*)(Wr + d*KK + koff);
            bf16x8 bi = *(const bf16x8*)(Wi + d*KK + koff);
            Prr[nt] = __builtin_amdgcn_mfma_f32_16x16x32_bf16(ar, br, Prr[nt], 0, 0, 0);
            Pii[nt] = __builtin_amdgcn_mfma_f32_16x16x32_bf16(ai, bi, Pii[nt], 0, 0, 0);
            Pri[nt] = __builtin_amdgcn_mfma_f32_16x16x32_bf16(ar, bi, Pri[nt], 0, 0, 0);
            Pir[nt] = __builtin_amdgcn_mfma_f32_16x16x32_bf16(ai, br, Pir[nt], 0, 0, 0);
        }
    }
    __syncthreads();                    // all agg reads done; reuse as dump

    // ---- dump partials: [wave][m][d] float2, rows m<8 only (quads 0,1) ----
    float2* dump = (float2*)aggS;       // 16384 B <= 18944
    if (quad < 2) {
        #pragma unroll
        for (int reg = 0; reg < 4; ++reg) {
            int m = quad*4 + reg;
            #pragma unroll
            for (int nt = 0; nt < 2; ++nt) {
                int d = nt*16 + nn16;
                dump[((size_t)g*NPB + m)*COUTC + d] =
                    make_float2(Prr[nt][reg] - Pii[nt][reg],
                                Pri[nt][reg] + Pir[nt][reg]);
            }
        }
    }
    __syncthreads();

    // ---- reduce 8 waves, residual, nonlinearity ----
    if (t < NPB*COUTC) {
        int m = t >> 5, d = t & 31;
        int n = nid[m];
        float2 hv = make_float2(0.f, 0.f);
        #pragma unroll
        for (int w = 0; w < NPB; ++w) {
            float2 v = dump[((size_t)w*NPB + m)*COUTC + d];
            hv.x += v.x; hv.y += v.y;
        }
        if (FINAL) {
            const float2* xr = xres + (size_t)n * CINC;
            #pragma unroll
            for (int c = 0; c < CINC; ++c) {
                float2 xv = xr[c];
                float2 w = resw[c*COUTC + d];
                hv.x += xv.x*w.x - xv.y*w.y;
                hv.y += xv.x*w.y + xv.y*w.x;
            }
        }
        float mag = sqrtf(hv.x*hv.x + hv.y*hv.y);
        float num = mag + bias[d]; if (num < 0.f) num = 0.f;
        float den = (mag > EPSV) ? mag : EPSV;
        float f = num / den;
        out[(size_t)n*COUTC + d] = make_float2(f*hv.x, f*hv.y);
    }
}

// ---------------- launch ----------------

extern "C" void kernel_launch(void* const* d_in, const int* in_sizes, int n_in,
                              void* d_out, int out_size, void* d_ws, size_t ws_size,
                              hipStream_t stream) {
    const float2* xc   = (const float2*)d_in[0];   // (N,32,2) -> complex
    const int*   edges = (const int*)  d_in[1];    // (E,2)
    const float4* stenc4 = (const float4*)d_in[2]; // (E,6,3,2) -> (E,9) float4
    const float* w1    = (const float*)d_in[3];
    const float* off1  = (const float*)d_in[4];
    const float* b1    = (const float*)d_in[5];
    const float* w2    = (const float*)d_in[6];
    const float* off2  = (const float*)d_in[7];
    const float* b2    = (const float*)d_in[8];
    const float2* resw = (const float2*)d_in[9];   // (32,32) complex
    float2* out = (float2*)d_out;

    char* ws = (char*)d_ws;
    size_t o = 0;
    auto alloc = [&](size_t bytes) {
        o = (o + 255) & ~(size_t)255;
        size_t r = o; o += bytes; return r;
    };
    int*    cursor = (int*)  (ws + alloc(NN*sizeof(int)));
    int*    order  = (int*)  (ws + alloc(NN*sizeof(int)));
    int2*   sei    = (int2*) (ws + alloc((size_t)NN*CAP*sizeof(int2)));
    short*  Wcb1   = (short*)(ws + alloc((size_t)2*KK*COUTC*sizeof(short)));
    short*  Wcb2   = (short*)(ws + alloc((size_t)2*KK*COUTC*sizeof(short)));
    short*  stenB  = (short*)(ws + alloc((size_t)EE*SBS*sizeof(short)));
    float2* h      = (float2*)(ws + alloc((size_t)NN*COUTC*sizeof(float2)));
    (void)ws_size; (void)in_sizes; (void)n_in; (void)out_size;

    hipMemsetAsync(cursor, 0, NN*sizeof(int), stream);
    k_build<<<(EE*9+255)/256, 256, 0, stream>>>(edges, cursor, w1, off1, w2, off2,
                                                Wcb1, Wcb2, sei, stenc4, stenB);
    k_order<<<1, 1024, 0, stream>>>(cursor, order);

    k_conv<false><<<NN/NPB, 512, 0, stream>>>(xc, cursor, order, sei,
                                              (const uint4*)stenB, Wcb1, b1,
                                              nullptr, nullptr, h);
    k_conv<true> <<<NN/NPB, 512, 0, stream>>>(h, cursor, order, sei,
                                              (const uint4*)stenB, Wcb2, b2,
                                              xc, resw, out);
}